// Round 1
// baseline (398.214 us; speedup 1.0000x reference)
//
#include <hip/hip_runtime.h>
#include <hip/hip_bf16.h>
#include <stdint.h>

typedef __bf16 bf16;
typedef __attribute__((ext_vector_type(8))) __bf16 bf16x8;
typedef __attribute__((ext_vector_type(4))) __bf16 bf16x4;
typedef __attribute__((ext_vector_type(4))) float  f32x4;

#define TILE 128
#define BK   64
#define NT   256

// ---- async global->LDS, 16B per lane, dest = uniform base + lane*16 ----
static __device__ __forceinline__ void gll16(const void* g, void* lds_base) {
  __builtin_amdgcn_global_load_lds((__attribute__((address_space(1))) void*)g,
                                   (__attribute__((address_space(3))) void*)lds_base,
                                   16, 0, 0);
}

// stage a TILE x BK bf16 tile (global row-major, ld elements) into linear LDS [TILE][BK]
static __device__ __forceinline__ void stage_bf16(const bf16* gtile, int ld, bf16* lds, int tid) {
  const int wave = tid >> 6, lane = tid & 63;
#pragma unroll
  for (int r = 0; r < (TILE * BK * 2) / (NT * 16); ++r) {   // 4 rounds
    const int base = (r * (NT / 64) + wave) << 10;          // wave-uniform byte base
    const int off  = base + lane * 16;
    const int row  = off >> 7;                              // / (BK*2)
    const int kb   = off & 127;
    gll16((const char*)(gtile + (size_t)row * ld) + kb, (char*)lds + base);
  }
}

// stage a TILE x BK fp32 tile, converting to bf16, into linear LDS [TILE][BK]
static __device__ __forceinline__ void stage_f32(const float* gtile, int ld, bf16* lds, int tid) {
#pragma unroll
  for (int r = 0; r < (TILE * BK) / (NT * 4); ++r) {        // 8 rounds
    const int idx = (r * NT + tid) * 4;
    const int row = idx >> 6;                               // / BK
    const int k   = idx & 63;
    const f32x4 f = *(const f32x4*)(gtile + (size_t)row * ld + k);
    bf16x4 h = { (bf16)f[0], (bf16)f[1], (bf16)f[2], (bf16)f[3] };
    *(bf16x4*)(lds + row * BK + k) = h;
  }
}

// one BK-deep MFMA step: each wave computes a 64x64 sub-tile (4x4 fragments of 16x16)
static __device__ __forceinline__ void mma_tile(const bf16* sA, const bf16* sB,
                                                f32x4 acc[4][4], int lane, int wm, int wn) {
  const int lo = lane & 15, hi = lane >> 4;
#pragma unroll
  for (int kk = 0; kk < BK; kk += 32) {
    bf16x8 a[4], b[4];
#pragma unroll
    for (int m = 0; m < 4; ++m)
      a[m] = *(const bf16x8*)(sA + (wm + m * 16 + lo) * BK + kk + hi * 8);
#pragma unroll
    for (int n = 0; n < 4; ++n)
      b[n] = *(const bf16x8*)(sB + (wn + n * 16 + lo) * BK + kk + hi * 8);
#pragma unroll
    for (int m = 0; m < 4; ++m)
#pragma unroll
      for (int n = 0; n < 4; ++n)
        acc[m][n] = __builtin_amdgcn_mfma_f32_16x16x32_bf16(a[m], b[n], acc[m][n], 0, 0, 0);
  }
}

// ---- fp32 -> bf16 elementwise (for weights) ----
__global__ __launch_bounds__(256) void cvt_kernel(const float* __restrict__ src,
                                                  bf16* __restrict__ dst, int n) {
  const int i = (blockIdx.x * 256 + threadIdx.x) * 8;
  if (i >= n) return;
  const f32x4 a = *(const f32x4*)(src + i);
  const f32x4 b = *(const f32x4*)(src + i + 4);
  bf16x8 o = { (bf16)a[0], (bf16)a[1], (bf16)a[2], (bf16)a[3],
               (bf16)b[0], (bf16)b[1], (bf16)b[2], (bf16)b[3] };
  *(bf16x8*)(dst + i) = o;
}

// ---- projection: Y[t,h] = sum_e X[t,e] * W[h,e]; X fp32, W bf16, Y bf16 ----
// TRANS=false: Y row-major [M][N].  TRANS=true: Y = per-batch transposed [B][N][1024] (v^T).
template <bool TRANS>
__global__ __launch_bounds__(NT) void proj_kernel(const float* __restrict__ X,
                                                  const bf16* __restrict__ W,
                                                  bf16* __restrict__ Y,
                                                  int M, int N, int K) {
  __shared__ bf16 sA[TILE * BK];
  __shared__ bf16 sB[TILE * BK];
  const int tid = threadIdx.x, lane = tid & 63, wave = tid >> 6;
  const int tiles_n = N / TILE;
  const int tn = blockIdx.x % tiles_n, tm = blockIdx.x / tiles_n;
  const int row0 = tm * TILE, col0 = tn * TILE;
  const int wm = (wave >> 1) * 64, wn = (wave & 1) * 64;
  f32x4 acc[4][4] = {};

  for (int kt = 0; kt < K; kt += BK) {
    stage_bf16(W + (size_t)col0 * K + kt, K, sB, tid);   // async DMA first
    stage_f32 (X + (size_t)row0 * K + kt, K, sA, tid);   // reg-stage + cvt overlaps
    __syncthreads();
    mma_tile(sA, sB, acc, lane, wm, wn);
    __syncthreads();
  }

  const int lo = lane & 15, hi = lane >> 4;
#pragma unroll
  for (int m = 0; m < 4; ++m) {
#pragma unroll
    for (int n = 0; n < 4; ++n) {
      const int r = row0 + wm + m * 16 + hi * 4;
      const int c = col0 + wn + n * 16 + lo;
      if (!TRANS) {
#pragma unroll
        for (int j = 0; j < 4; ++j)
          Y[(size_t)(r + j) * N + c] = (bf16)acc[m][n][j];
      } else {
        const int b = r >> 10, t = r & 1023;               // fragment rows stay in one batch
        bf16x4 h = { (bf16)acc[m][n][0], (bf16)acc[m][n][1],
                     (bf16)acc[m][n][2], (bf16)acc[m][n][3] };
        *(bf16x4*)(Y + ((size_t)b << 20) + ((size_t)c << 10) + t) = h;
      }
    }
  }
}

// ---- S = scale * Q K^T with causal(diag=+1) + padding mask, bf16 out ----
__global__ __launch_bounds__(NT) void qk_kernel(const bf16* __restrict__ Q,
                                                const bf16* __restrict__ Km,
                                                const int* __restrict__ pad,
                                                bf16* __restrict__ S) {
  const int b  = blockIdx.y;
  const int jt = blockIdx.x & 7, it = blockIdx.x >> 3;
  bf16* Sb = S + ((size_t)b << 20);
  const int row0 = it * TILE, col0 = jt * TILE;

  if (jt >= it + 2) {  // fully masked tile: pure -inf fill
    const bf16 NI = (bf16)(-__builtin_inff());
    bf16x8 fill = { NI, NI, NI, NI, NI, NI, NI, NI };
    const int tid = threadIdx.x;
#pragma unroll
    for (int r = 0; r < 8; ++r) {
      const int off = (r * NT + tid) * 8;
      const int rr = off >> 7, cc = off & 127;
      *(bf16x8*)(Sb + (size_t)(row0 + rr) * 1024 + col0 + cc) = fill;
    }
    return;
  }

  __shared__ bf16 sA[TILE * BK];
  __shared__ bf16 sB[TILE * BK];
  const int tid = threadIdx.x, lane = tid & 63, wave = tid >> 6;
  const int wm = (wave >> 1) * 64, wn = (wave & 1) * 64;
  const bf16* Qb = Q + ((size_t)b << 20);
  const bf16* Kb = Km + ((size_t)b << 20);
  f32x4 acc[4][4] = {};

  for (int kt = 0; kt < 1024; kt += BK) {
    stage_bf16(Qb + (size_t)row0 * 1024 + kt, 1024, sA, tid);
    stage_bf16(Kb + (size_t)col0 * 1024 + kt, 1024, sB, tid);
    __syncthreads();
    mma_tile(sA, sB, acc, lane, wm, wn);
    __syncthreads();
  }

  const int lo = lane & 15, hi = lane >> 4;
  const float NINF = -__builtin_inff();
#pragma unroll
  for (int m = 0; m < 4; ++m) {
#pragma unroll
    for (int n = 0; n < 4; ++n) {
      const int s = col0 + wn + n * 16 + lo;
      const int pd = pad[b * 1024 + s];
#pragma unroll
      for (int j = 0; j < 4; ++j) {
        const int t = row0 + wm + m * 16 + hi * 4 + j;
        float v = acc[m][n][j] * 0.03125f;               // 1/sqrt(1024)
        if (s > t + 1 || pd != 0) v = NINF;
        Sb[(size_t)t * 1024 + s] = (bf16)v;
      }
    }
  }
}

// ---- row softmax in place: one wave per 1024-wide row ----
__global__ __launch_bounds__(256) void softmax_kernel(bf16* __restrict__ S) {
  const int row  = blockIdx.x * 4 + (threadIdx.x >> 6);
  const int lane = threadIdx.x & 63;
  bf16* r = S + (size_t)row * 1024 + lane * 16;
  bf16x8 v0 = *(const bf16x8*)r;
  bf16x8 v1 = *(const bf16x8*)(r + 8);
  float f[16];
#pragma unroll
  for (int j = 0; j < 8; ++j) { f[j] = (float)v0[j]; f[8 + j] = (float)v1[j]; }
  float m = f[0];
#pragma unroll
  for (int j = 1; j < 16; ++j) m = fmaxf(m, f[j]);
#pragma unroll
  for (int o = 32; o; o >>= 1) m = fmaxf(m, __shfl_xor(m, o, 64));
  float sum = 0.f;
#pragma unroll
  for (int j = 0; j < 16; ++j) { f[j] = __expf(f[j] - m); sum += f[j]; }
#pragma unroll
  for (int o = 32; o; o >>= 1) sum += __shfl_xor(sum, o, 64);
  const float inv = 1.0f / sum;
#pragma unroll
  for (int j = 0; j < 8; ++j) { v0[j] = (bf16)(f[j] * inv); v1[j] = (bf16)(f[8 + j] * inv); }
  *(bf16x8*)r = v0;
  *(bf16x8*)(r + 8) = v1;
}

// ---- O[t,h] = sum_s P[t,s] * VT[h,s]; fp32 out; K loop causally truncated ----
__global__ __launch_bounds__(NT) void pv_kernel(const bf16* __restrict__ P,
                                                const bf16* __restrict__ VT,
                                                float* __restrict__ O) {
  const int b  = blockIdx.y;
  const int jt = blockIdx.x & 7, it = blockIdx.x >> 3;
  const bf16* Pb = P  + ((size_t)b << 20);
  const bf16* Vb = VT + ((size_t)b << 20);
  float* Ob = O + ((size_t)b << 20);
  const int row0 = it * TILE, col0 = jt * TILE;
  const int kend = min(1024, row0 + 192);   // valid s <= t+1 <= row0+128; rest of P is exact 0

  __shared__ bf16 sA[TILE * BK];
  __shared__ bf16 sB[TILE * BK];
  const int tid = threadIdx.x, lane = tid & 63, wave = tid >> 6;
  const int wm = (wave >> 1) * 64, wn = (wave & 1) * 64;
  f32x4 acc[4][4] = {};

  for (int kt = 0; kt < kend; kt += BK) {
    stage_bf16(Pb + (size_t)row0 * 1024 + kt, 1024, sA, tid);
    stage_bf16(Vb + (size_t)col0 * 1024 + kt, 1024, sB, tid);
    __syncthreads();
    mma_tile(sA, sB, acc, lane, wm, wn);
    __syncthreads();
  }

  const int lo = lane & 15, hi = lane >> 4;
#pragma unroll
  for (int m = 0; m < 4; ++m) {
#pragma unroll
    for (int n = 0; n < 4; ++n) {
      const int h = col0 + wn + n * 16 + lo;
#pragma unroll
      for (int j = 0; j < 4; ++j) {
        const int t = row0 + wm + m * 16 + hi * 4 + j;
        Ob[(size_t)t * 1024 + h] = acc[m][n][j];
      }
    }
  }
}

extern "C" void kernel_launch(void* const* d_in, const int* in_sizes, int n_in,
                              void* d_out, int out_size, void* d_ws, size_t ws_size,
                              hipStream_t stream) {
  const float* key   = (const float*)d_in[0];
  const float* query = (const float*)d_in[1];
  const float* value = (const float*)d_in[2];
  const int*   pad   = (const int*)d_in[3];
  const float* Wk    = (const float*)d_in[4];
  const float* Wq    = (const float*)d_in[5];
  const float* Wv    = (const float*)d_in[6];
  float* out = (float*)d_out;

  // ws layout (bf16 elements): Wk,Wq,Wv (1M each) | q (16M) | k (16M) | vT (16M) | S (16M)
  bf16* Wkb = (bf16*)d_ws;
  bf16* Wqb = Wkb + (1 << 20);
  bf16* Wvb = Wqb + (1 << 20);
  bf16* qb  = Wvb + (1 << 20);
  bf16* kb  = qb  + (16 << 20);
  bf16* vT  = kb  + (16 << 20);
  bf16* S   = vT  + (16 << 20);

  cvt_kernel<<<512, 256, 0, stream>>>(Wk, Wkb, 1 << 20);
  cvt_kernel<<<512, 256, 0, stream>>>(Wq, Wqb, 1 << 20);
  cvt_kernel<<<512, 256, 0, stream>>>(Wv, Wvb, 1 << 20);

  const dim3 pg(128 * 8);
  proj_kernel<false><<<pg, NT, 0, stream>>>(query, Wqb, qb, 16384, 1024, 1024);
  proj_kernel<false><<<pg, NT, 0, stream>>>(key,   Wkb, kb, 16384, 1024, 1024);
  proj_kernel<true ><<<pg, NT, 0, stream>>>(value, Wvb, vT, 16384, 1024, 1024);

  qk_kernel<<<dim3(64, 16), NT, 0, stream>>>(qb, kb, pad, S);
  softmax_kernel<<<4096, 256, 0, stream>>>(S);
  pv_kernel<<<dim3(64, 16), NT, 0, stream>>>(S, vT, out);
}

// Round 2
// 360.754 us; speedup vs baseline: 1.1038x; 1.1038x over previous
//
#include <hip/hip_runtime.h>
#include <hip/hip_bf16.h>
#include <stdint.h>

typedef __bf16 bf16;
typedef __attribute__((ext_vector_type(8))) __bf16 bf16x8;
typedef __attribute__((ext_vector_type(4))) __bf16 bf16x4;
typedef __attribute__((ext_vector_type(4))) float  f32x4;

#define TILE 128
#define BK   64
#define NT   256

// ---- async global->LDS, 16B per lane, dest = uniform base + lane*16 ----
static __device__ __forceinline__ void gll16(const void* g, void* lds_base) {
  __builtin_amdgcn_global_load_lds((__attribute__((address_space(1))) void*)g,
                                   (__attribute__((address_space(3))) void*)lds_base,
                                   16, 0, 0);
}

// stage a TILE x BK bf16 tile (global row-major, ld elements) into linear LDS [TILE][BK]
static __device__ __forceinline__ void stage_bf16(const bf16* gtile, int ld, bf16* lds, int tid) {
  const int wave = tid >> 6, lane = tid & 63;
#pragma unroll
  for (int r = 0; r < (TILE * BK * 2) / (NT * 16); ++r) {   // 4 rounds
    const int base = (r * (NT / 64) + wave) << 10;          // wave-uniform byte base
    const int off  = base + lane * 16;
    const int row  = off >> 7;                              // / (BK*2)
    const int kb   = off & 127;
    gll16((const char*)(gtile + (size_t)row * ld) + kb, (char*)lds + base);
  }
}

// one BK-deep MFMA step: each wave computes a 64x64 sub-tile (4x4 fragments of 16x16)
static __device__ __forceinline__ void mma_tile(const bf16* sA, const bf16* sB,
                                                f32x4 acc[4][4], int lane, int wm, int wn) {
  const int lo = lane & 15, hi = lane >> 4;
#pragma unroll
  for (int kk = 0; kk < BK; kk += 32) {
    bf16x8 a[4], b[4];
#pragma unroll
    for (int m = 0; m < 4; ++m)
      a[m] = *(const bf16x8*)(sA + (wm + m * 16 + lo) * BK + kk + hi * 8);
#pragma unroll
    for (int n = 0; n < 4; ++n)
      b[n] = *(const bf16x8*)(sB + (wn + n * 16 + lo) * BK + kk + hi * 8);
#pragma unroll
    for (int m = 0; m < 4; ++m)
#pragma unroll
      for (int n = 0; n < 4; ++n)
        acc[m][n] = __builtin_amdgcn_mfma_f32_16x16x32_bf16(a[m], b[n], acc[m][n], 0, 0, 0);
  }
}

// ---- fp32 -> bf16 elementwise ----
__global__ __launch_bounds__(256) void cvt_kernel(const float* __restrict__ src,
                                                  bf16* __restrict__ dst, int n) {
  const int i = (blockIdx.x * 256 + threadIdx.x) * 8;
  if (i >= n) return;
  const f32x4 a = *(const f32x4*)(src + i);
  const f32x4 b = *(const f32x4*)(src + i + 4);
  bf16x8 o = { (bf16)a[0], (bf16)a[1], (bf16)a[2], (bf16)a[3],
               (bf16)b[0], (bf16)b[1], (bf16)b[2], (bf16)b[3] };
  *(bf16x8*)(dst + i) = o;
}

// ---- projection: Y[t,h] = sum_e X[t,e] * W[h,e]; X bf16, W bf16, Y bf16 ----
// TRANS=false: Y row-major [M][N].  TRANS=true: Y = per-batch transposed [B][N][1024] (v^T).
template <bool TRANS>
__global__ __launch_bounds__(NT) void proj_kernel(const bf16* __restrict__ X,
                                                  const bf16* __restrict__ W,
                                                  bf16* __restrict__ Y,
                                                  int M, int N, int K) {
  __shared__ bf16 sA[TILE * BK];
  __shared__ bf16 sB[TILE * BK];
  const int tid = threadIdx.x, lane = tid & 63, wave = tid >> 6;
  const int tiles_n = N / TILE;
  const int tn = blockIdx.x % tiles_n, tm = blockIdx.x / tiles_n;
  const int row0 = tm * TILE, col0 = tn * TILE;
  const int wm = (wave >> 1) * 64, wn = (wave & 1) * 64;
  f32x4 acc[4][4] = {};

  for (int kt = 0; kt < K; kt += BK) {
    stage_bf16(X + (size_t)row0 * K + kt, K, sA, tid);
    stage_bf16(W + (size_t)col0 * K + kt, K, sB, tid);
    __syncthreads();
    mma_tile(sA, sB, acc, lane, wm, wn);
    __syncthreads();
  }

  const int lo = lane & 15, hi = lane >> 4;
#pragma unroll
  for (int m = 0; m < 4; ++m) {
#pragma unroll
    for (int n = 0; n < 4; ++n) {
      const int r = row0 + wm + m * 16 + hi * 4;
      const int c = col0 + wn + n * 16 + lo;
      if (!TRANS) {
#pragma unroll
        for (int j = 0; j < 4; ++j)
          Y[(size_t)(r + j) * N + c] = (bf16)acc[m][n][j];
      } else {
        const int b = r >> 10, t = r & 1023;               // fragment rows stay in one batch
        bf16x4 h = { (bf16)acc[m][n][0], (bf16)acc[m][n][1],
                     (bf16)acc[m][n][2], (bf16)acc[m][n][3] };
        *(bf16x4*)(Y + ((size_t)b << 20) + ((size_t)c << 10) + t) = h;
      }
    }
  }
}

// ---- S = scale * Q K^T with causal(diag=+1) + padding mask, bf16 out ----
__global__ __launch_bounds__(NT) void qk_kernel(const bf16* __restrict__ Q,
                                                const bf16* __restrict__ Km,
                                                const int* __restrict__ pad,
                                                bf16* __restrict__ S) {
  const int b  = blockIdx.y;
  const int jt = blockIdx.x & 7, it = blockIdx.x >> 3;
  bf16* Sb = S + ((size_t)b << 20);
  const int row0 = it * TILE, col0 = jt * TILE;

  if (jt >= it + 2) {  // fully masked tile: pure -inf fill
    const bf16 NI = (bf16)(-__builtin_inff());
    bf16x8 fill = { NI, NI, NI, NI, NI, NI, NI, NI };
    const int tid = threadIdx.x;
#pragma unroll
    for (int r = 0; r < 8; ++r) {
      const int off = (r * NT + tid) * 8;
      const int rr = off >> 7, cc = off & 127;
      *(bf16x8*)(Sb + (size_t)(row0 + rr) * 1024 + col0 + cc) = fill;
    }
    return;
  }

  __shared__ bf16 sA[TILE * BK];
  __shared__ bf16 sB[TILE * BK];
  const int tid = threadIdx.x, lane = tid & 63, wave = tid >> 6;
  const int wm = (wave >> 1) * 64, wn = (wave & 1) * 64;
  const bf16* Qb = Q + ((size_t)b << 20);
  const bf16* Kb = Km + ((size_t)b << 20);
  f32x4 acc[4][4] = {};

  for (int kt = 0; kt < 1024; kt += BK) {
    stage_bf16(Qb + (size_t)row0 * 1024 + kt, 1024, sA, tid);
    stage_bf16(Kb + (size_t)col0 * 1024 + kt, 1024, sB, tid);
    __syncthreads();
    mma_tile(sA, sB, acc, lane, wm, wn);
    __syncthreads();
  }

  const int lo = lane & 15, hi = lane >> 4;
  const float NINF = -__builtin_inff();
#pragma unroll
  for (int m = 0; m < 4; ++m) {
#pragma unroll
    for (int n = 0; n < 4; ++n) {
      const int s = col0 + wn + n * 16 + lo;
      const int pd = pad[b * 1024 + s];
#pragma unroll
      for (int j = 0; j < 4; ++j) {
        const int t = row0 + wm + m * 16 + hi * 4 + j;
        float v = acc[m][n][j] * 0.03125f;               // 1/sqrt(1024)
        if (s > t + 1 || pd != 0) v = NINF;
        Sb[(size_t)t * 1024 + s] = (bf16)v;
      }
    }
  }
}

// ---- row softmax in place: one wave per 1024-wide row ----
__global__ __launch_bounds__(256) void softmax_kernel(bf16* __restrict__ S) {
  const int row  = blockIdx.x * 4 + (threadIdx.x >> 6);
  const int lane = threadIdx.x & 63;
  bf16* r = S + (size_t)row * 1024 + lane * 16;
  bf16x8 v0 = *(const bf16x8*)r;
  bf16x8 v1 = *(const bf16x8*)(r + 8);
  float f[16];
#pragma unroll
  for (int j = 0; j < 8; ++j) { f[j] = (float)v0[j]; f[8 + j] = (float)v1[j]; }
  float m = f[0];
#pragma unroll
  for (int j = 1; j < 16; ++j) m = fmaxf(m, f[j]);
#pragma unroll
  for (int o = 32; o; o >>= 1) m = fmaxf(m, __shfl_xor(m, o, 64));
  float sum = 0.f;
#pragma unroll
  for (int j = 0; j < 16; ++j) { f[j] = __expf(f[j] - m); sum += f[j]; }
#pragma unroll
  for (int o = 32; o; o >>= 1) sum += __shfl_xor(sum, o, 64);
  const float inv = 1.0f / sum;
#pragma unroll
  for (int j = 0; j < 8; ++j) { v0[j] = (bf16)(f[j] * inv); v1[j] = (bf16)(f[8 + j] * inv); }
  *(bf16x8*)r = v0;
  *(bf16x8*)(r + 8) = v1;
}

// ---- O[t,h] = sum_s P[t,s] * VT[h,s]; fp32 out; K loop causally truncated ----
__global__ __launch_bounds__(NT) void pv_kernel(const bf16* __restrict__ P,
                                                const bf16* __restrict__ VT,
                                                float* __restrict__ O) {
  const int b  = blockIdx.y;
  const int jt = blockIdx.x & 7, it = blockIdx.x >> 3;
  const bf16* Pb = P  + ((size_t)b << 20);
  const bf16* Vb = VT + ((size_t)b << 20);
  float* Ob = O + ((size_t)b << 20);
  const int row0 = it * TILE, col0 = jt * TILE;
  const int kend = min(1024, row0 + 192);   // valid s <= t+1 <= row0+128; rest of P is exact 0

  __shared__ bf16 sA[TILE * BK];
  __shared__ bf16 sB[TILE * BK];
  const int tid = threadIdx.x, lane = tid & 63, wave = tid >> 6;
  const int wm = (wave >> 1) * 64, wn = (wave & 1) * 64;
  f32x4 acc[4][4] = {};

  for (int kt = 0; kt < kend; kt += BK) {
    stage_bf16(Pb + (size_t)row0 * 1024 + kt, 1024, sA, tid);
    stage_bf16(Vb + (size_t)col0 * 1024 + kt, 1024, sB, tid);
    __syncthreads();
    mma_tile(sA, sB, acc, lane, wm, wn);
    __syncthreads();
  }

  const int lo = lane & 15, hi = lane >> 4;
#pragma unroll
  for (int m = 0; m < 4; ++m) {
#pragma unroll
    for (int n = 0; n < 4; ++n) {
      const int h = col0 + wn + n * 16 + lo;
#pragma unroll
      for (int j = 0; j < 4; ++j) {
        const int t = row0 + wm + m * 16 + hi * 4 + j;
        Ob[(size_t)t * 1024 + h] = acc[m][n][j];
      }
    }
  }
}

extern "C" void kernel_launch(void* const* d_in, const int* in_sizes, int n_in,
                              void* d_out, int out_size, void* d_ws, size_t ws_size,
                              hipStream_t stream) {
  const float* key   = (const float*)d_in[0];
  const float* query = (const float*)d_in[1];
  const float* value = (const float*)d_in[2];
  const int*   pad   = (const int*)d_in[3];
  const float* Wk    = (const float*)d_in[4];
  const float* Wq    = (const float*)d_in[5];
  const float* Wv    = (const float*)d_in[6];
  float* out = (float*)d_out;

  // ws layout (bf16 elements): Wk,Wq,Wv (1M each) | q (16M) | k (16M) | vT (16M) | S (16M)
  // S doubles as the bf16-X scratch during the projection phase (not live until qk).
  bf16* Wkb = (bf16*)d_ws;
  bf16* Wqb = Wkb + (1 << 20);
  bf16* Wvb = Wqb + (1 << 20);
  bf16* qb  = Wvb + (1 << 20);
  bf16* kb  = qb  + (16 << 20);
  bf16* vT  = kb  + (16 << 20);
  bf16* S   = vT  + (16 << 20);
  bf16* Xb  = S;                       // alias: projection-phase scratch

  cvt_kernel<<<512, 256, 0, stream>>>(Wk, Wkb, 1 << 20);
  cvt_kernel<<<512, 256, 0, stream>>>(Wq, Wqb, 1 << 20);
  cvt_kernel<<<512, 256, 0, stream>>>(Wv, Wvb, 1 << 20);

  const dim3 pg(128 * 8);
  cvt_kernel<<<8192, 256, 0, stream>>>(query, Xb, 16 << 20);
  proj_kernel<false><<<pg, NT, 0, stream>>>(Xb, Wqb, qb, 16384, 1024, 1024);
  cvt_kernel<<<8192, 256, 0, stream>>>(key, Xb, 16 << 20);
  proj_kernel<false><<<pg, NT, 0, stream>>>(Xb, Wkb, kb, 16384, 1024, 1024);
  cvt_kernel<<<8192, 256, 0, stream>>>(value, Xb, 16 << 20);
  proj_kernel<true ><<<pg, NT, 0, stream>>>(Xb, Wvb, vT, 16384, 1024, 1024);

  qk_kernel<<<dim3(64, 16), NT, 0, stream>>>(qb, kb, pad, S);
  softmax_kernel<<<4096, 256, 0, stream>>>(S);
  pv_kernel<<<dim3(64, 16), NT, 0, stream>>>(S, vT, out);
}

// Round 3
// 310.347 us; speedup vs baseline: 1.2831x; 1.1624x over previous
//
#include <hip/hip_runtime.h>
#include <hip/hip_bf16.h>
#include <stdint.h>

typedef __bf16 bf16;
typedef __attribute__((ext_vector_type(8))) __bf16 bf16x8;
typedef __attribute__((ext_vector_type(4))) __bf16 bf16x4;
typedef __attribute__((ext_vector_type(4))) float  f32x4;

// ---- async global->LDS, 16B per lane, dest = wave-uniform base (+ lane*16 in HW) ----
static __device__ __forceinline__ void gll16(const void* g, void* lds_base) {
  __builtin_amdgcn_global_load_lds((__attribute__((address_space(1))) void*)g,
                                   (__attribute__((address_space(3))) void*)lds_base,
                                   16, 0, 0);
}

// ============================================================================
// 256x256 BT-GEMM (D = A * B^T, both operands K-contiguous, ld = 1024), BK=64,
// 8 waves (2M x 4N), 8-phase schedule, double-buffered 128 KiB LDS,
// st_16x32 swizzle (linear gll dest + inverse-swizzled global src + swizzled
// ds_read), counted vmcnt(4) twice per iteration (never 0 in the loop).
// VARIANT: 0 proj -> Cb row-major [M][1024] bf16
//          1 proj -> Cb = per-batch transposed v^T [b][h][t] bf16
//          2 qk   -> Cb = S bf16 (scale, causal diag=+1, padding mask);
//                    upper-triangle tiles are -inf fill-only blocks
//          3 pv   -> Cf = O f32, K-loop causally truncated
// ============================================================================
#define NOOPV (void)0
#define PHASE(CUR, MQ, NQ, S0, S1, VMW)                                        \
  do {                                                                         \
    bf16x8 af[4][2], bfr[2][2];                                                \
    _Pragma("unroll") for (int i_ = 0; i_ < 4; ++i_)                           \
    _Pragma("unroll") for (int kh_ = 0; kh_ < 2; ++kh_) {                      \
      const int row_ = wmi * 128 + MQ * 64 + i_ * 16 + lo;                     \
      const int ab_ = (row_ * 128 + kh_ * 64 + hi * 16) ^ swz5;                \
      af[i_][kh_] = *(const bf16x8*)(ldsA + (CUR) * 32768 + ab_);              \
    }                                                                          \
    _Pragma("unroll") for (int j_ = 0; j_ < 2; ++j_)                           \
    _Pragma("unroll") for (int kh_ = 0; kh_ < 2; ++kh_) {                      \
      const int row_ = wni * 64 + NQ * 32 + j_ * 16 + lo;                      \
      const int ab_ = (row_ * 128 + kh_ * 64 + hi * 16) ^ swz5;                \
      bfr[j_][kh_] = *(const bf16x8*)(ldsB + (CUR) * 32768 + ab_);             \
    }                                                                          \
    S0; S1;                                                                    \
    __builtin_amdgcn_s_barrier();                                              \
    asm volatile("s_waitcnt lgkmcnt(0)" ::: "memory");                         \
    __builtin_amdgcn_sched_barrier(0);                                         \
    __builtin_amdgcn_s_setprio(1);                                             \
    _Pragma("unroll") for (int i_ = 0; i_ < 4; ++i_)                           \
    _Pragma("unroll") for (int j_ = 0; j_ < 2; ++j_)                           \
    _Pragma("unroll") for (int kh_ = 0; kh_ < 2; ++kh_)                        \
      acc[MQ * 4 + i_][NQ * 2 + j_] = __builtin_amdgcn_mfma_f32_16x16x32_bf16( \
          af[i_][kh_], bfr[j_][kh_], acc[MQ * 4 + i_][NQ * 2 + j_], 0, 0, 0);  \
    __builtin_amdgcn_s_setprio(0);                                             \
    VMW;                                                                       \
    __builtin_amdgcn_s_barrier();                                              \
  } while (0)

template <int VARIANT>
__global__ __launch_bounds__(512, 2) void gemm8(const bf16* __restrict__ A,
                                                const bf16* __restrict__ B,
                                                bf16* __restrict__ Cb,
                                                float* __restrict__ Cf,
                                                const int* __restrict__ pad) {
  extern __shared__ char smem[];         // A: 2 x 32KB | B: 2 x 32KB
  char* ldsA = smem;
  char* ldsB = smem + 65536;

  const int tid = threadIdx.x;
  const int lane = tid & 63, wave = tid >> 6;
  const int lo = lane & 15, hi = lane >> 4;
  const int wmi = wave >> 2, wni = wave & 3;
  const int swz5 = ((lo >> 2) & 1) << 5;   // st_16x32: bit9 of addr == bit2 of row == bit2 of lo

  // XCD-chunked bijective swizzle (gridDim.x % 8 == 0 for all launches)
  const int nwg = gridDim.x;
  const int id = (blockIdx.x % 8) * (nwg >> 3) + blockIdx.x / 8;

  int row0, col0, nt, b = 0;
  if (VARIANT <= 1) {
    row0 = (id >> 2) * 256; col0 = (id & 3) * 256; nt = 16;
  } else {
    b = id >> 4;
    const int r = id & 15, it = r >> 2, jt = r & 3;
    row0 = it * 256; col0 = jt * 256;
    nt = (VARIANT == 3) ? min(16, 6 + 4 * it) : 16;
    if (VARIANT == 2 && jt > it) {
      // fully-masked tile (except the jt==it+1 corner, fixed by corner_kernel)
      bf16* Sb = Cb + ((size_t)b << 20);
      const bf16 NI = (bf16)(-__builtin_inff());
      bf16x8 fill = { NI, NI, NI, NI, NI, NI, NI, NI };
#pragma unroll
      for (int q = 0; q < 16; ++q) {                 // 256x256 elems / (512 thr * 8)
        const int off = (q * 512 + tid) * 8;
        const int rr = off >> 8, cc = off & 255;
        *(bf16x8*)(Sb + (size_t)(row0 + rr) * 1024 + col0 + cc) = fill;
      }
      return;
    }
  }
  const bf16* Ap = A + ((size_t)b << 20) + (size_t)row0 * 1024;
  const bf16* Bp = B + ((size_t)b << 20) + (size_t)col0 * 1024;
  const int ntm1 = nt - 1;

  // stage 64 rows (rowblock..rowblock+63) of K-tile tidx into slot; linear LDS
  // dest, inverse-swizzled global source (same involution as the ds_read).
  auto stgA = [&](int rowblock, int slot, int tidx) {
    const int tc = tidx > ntm1 ? ntm1 : tidx;        // clamp: slot never read again
    const int x  = rowblock * 128 + tid * 16;
    const int xs = x ^ (((x >> 9) & 1) << 5);
    gll16((const char*)Ap + (size_t)(xs >> 7) * 2048 + tc * 128 + (xs & 127),
          ldsA + slot * 32768 + rowblock * 128 + wave * 1024);
  };
  auto stgB = [&](int rowblock, int slot, int tidx) {
    const int tc = tidx > ntm1 ? ntm1 : tidx;
    const int x  = rowblock * 128 + tid * 16;
    const int xs = x ^ (((x >> 9) & 1) << 5);
    gll16((const char*)Bp + (size_t)(xs >> 7) * 2048 + tc * 128 + (xs & 127),
          ldsB + slot * 32768 + rowblock * 128 + wave * 1024);
  };

  f32x4 acc[8][4] = {};

  // prologue: A0(0) B0(0) A1(0) B1(0) A0(1) B0(1); vmcnt(4) => tile0 landed,
  // {A0,B0}(1) in flight — matches the steady-state invariant at phase 0.
  stgA(0, 0, 0);  stgA(128, 0, 0);
  stgB(0, 0, 0);  stgB(128, 0, 0);
  stgA(64, 0, 0); stgA(192, 0, 0);
  stgB(64, 0, 0); stgB(192, 0, 0);
  stgA(0, 1, 1);  stgA(128, 1, 1);
  stgB(0, 1, 1);  stgB(128, 1, 1);
  asm volatile("s_waitcnt vmcnt(4)" ::: "memory");
  __builtin_amdgcn_s_barrier();

  const int niter = nt >> 1;                         // nt is always even here
  for (int i = 0; i < niter; ++i) {
    const int t = 2 * i;                             // even tile -> slot0, odd -> slot1
    PHASE(0, 0, 0, stgA(64, 1, t + 1),  stgA(192, 1, t + 1), NOOPV);
    PHASE(0, 0, 1, stgB(64, 1, t + 1),  stgB(192, 1, t + 1), NOOPV);
    PHASE(0, 1, 0, stgA(0, 0, t + 2),   stgA(128, 0, t + 2), NOOPV);
    PHASE(0, 1, 1, stgB(0, 0, t + 2),   stgB(128, 0, t + 2),
          asm volatile("s_waitcnt vmcnt(4)" ::: "memory"));
    PHASE(1, 0, 0, stgA(64, 0, t + 2),  stgA(192, 0, t + 2), NOOPV);
    PHASE(1, 0, 1, stgB(64, 0, t + 2),  stgB(192, 0, t + 2), NOOPV);
    PHASE(1, 1, 0, stgA(0, 1, t + 3),   stgA(128, 1, t + 3), NOOPV);
    PHASE(1, 1, 1, stgB(0, 1, t + 3),   stgB(128, 1, t + 3),
          asm volatile("s_waitcnt vmcnt(4)" ::: "memory"));
  }

  // ---- epilogue ----
  if (VARIANT == 0) {
#pragma unroll
    for (int m = 0; m < 8; ++m)
#pragma unroll
      for (int n = 0; n < 4; ++n) {
        const int c = col0 + wni * 64 + n * 16 + lo;
        const int rbase = row0 + wmi * 128 + m * 16 + hi * 4;
#pragma unroll
        for (int j = 0; j < 4; ++j)
          Cb[(size_t)(rbase + j) * 1024 + c] = (bf16)acc[m][n][j];
      }
  } else if (VARIANT == 1) {
#pragma unroll
    for (int m = 0; m < 8; ++m)
#pragma unroll
      for (int n = 0; n < 4; ++n) {
        const int r = row0 + wmi * 128 + m * 16 + hi * 4;
        const int c = col0 + wni * 64 + n * 16 + lo;
        const int bb = r >> 10, tt = r & 1023;
        bf16x4 h = { (bf16)acc[m][n][0], (bf16)acc[m][n][1],
                     (bf16)acc[m][n][2], (bf16)acc[m][n][3] };
        *(bf16x4*)(Cb + ((size_t)bb << 20) + ((size_t)c << 10) + tt) = h;
      }
  } else if (VARIANT == 2) {
    const float NINF = -__builtin_inff();
#pragma unroll
    for (int n = 0; n < 4; ++n) {
      const int s = col0 + wni * 64 + n * 16 + lo;
      const int pd = pad[(b << 10) + s];
#pragma unroll
      for (int m = 0; m < 8; ++m) {
        const int tbase = row0 + wmi * 128 + m * 16 + hi * 4;
#pragma unroll
        for (int j = 0; j < 4; ++j) {
          float v = acc[m][n][j] * 0.03125f;          // 1/sqrt(1024)
          if (s > tbase + j + 1 || pd != 0) v = NINF;
          Cb[((size_t)b << 20) + (size_t)(tbase + j) * 1024 + s] = (bf16)v;
        }
      }
    }
  } else {
#pragma unroll
    for (int m = 0; m < 8; ++m)
#pragma unroll
      for (int n = 0; n < 4; ++n) {
        const int h2 = col0 + wni * 64 + n * 16 + lo;
        const int tbase = row0 + wmi * 128 + m * 16 + hi * 4;
#pragma unroll
        for (int j = 0; j < 4; ++j)
          Cf[((size_t)b << 20) + (size_t)(tbase + j) * 1024 + h2] = acc[m][n][j];
      }
  }
  asm volatile("s_waitcnt vmcnt(0)" ::: "memory");   // drain clamped stages before exit
}

// ---- fp32 -> bf16 elementwise ----
__global__ __launch_bounds__(256) void cvt_kernel(const float* __restrict__ src,
                                                  bf16* __restrict__ dst, int n) {
  const int i = (blockIdx.x * 256 + threadIdx.x) * 8;
  if (i >= n) return;
  const f32x4 a = *(const f32x4*)(src + i);
  const f32x4 b = *(const f32x4*)(src + i + 4);
  bf16x8 o = { (bf16)a[0], (bf16)a[1], (bf16)a[2], (bf16)a[3],
               (bf16)b[0], (bf16)b[1], (bf16)b[2], (bf16)b[3] };
  *(bf16x8*)(dst + i) = o;
}

// ---- the single valid element on each jt==it+1 tile: S[t=it*256+255][s=(it+1)*256] ----
__global__ __launch_bounds__(64) void corner_kernel(const bf16* __restrict__ Q,
                                                    const bf16* __restrict__ K,
                                                    const int* __restrict__ pad,
                                                    bf16* __restrict__ S) {
  const int b = blockIdx.x / 3, it = blockIdx.x % 3;
  const int t = it * 256 + 255, s = (it + 1) * 256;
  const int lane = threadIdx.x;
  const bf16* q = Q + ((size_t)b << 20) + (size_t)t * 1024 + lane * 16;
  const bf16* k = K + ((size_t)b << 20) + (size_t)s * 1024 + lane * 16;
  bf16x8 q0 = *(const bf16x8*)q, q1 = *(const bf16x8*)(q + 8);
  bf16x8 k0 = *(const bf16x8*)k, k1 = *(const bf16x8*)(k + 8);
  float d = 0.f;
#pragma unroll
  for (int j = 0; j < 8; ++j) d += (float)q0[j] * (float)k0[j] + (float)q1[j] * (float)k1[j];
#pragma unroll
  for (int o = 32; o; o >>= 1) d += __shfl_xor(d, o, 64);
  if (lane == 0) {
    float v = d * 0.03125f;
    if (pad[(b << 10) + s] != 0) v = -__builtin_inff();
    S[((size_t)b << 20) + (size_t)t * 1024 + s] = (bf16)v;
  }
}

// ---- row softmax in place: one wave per 1024-wide row ----
__global__ __launch_bounds__(256) void softmax_kernel(bf16* __restrict__ S) {
  const int row  = blockIdx.x * 4 + (threadIdx.x >> 6);
  const int lane = threadIdx.x & 63;
  bf16* r = S + (size_t)row * 1024 + lane * 16;
  bf16x8 v0 = *(const bf16x8*)r;
  bf16x8 v1 = *(const bf16x8*)(r + 8);
  float f[16];
#pragma unroll
  for (int j = 0; j < 8; ++j) { f[j] = (float)v0[j]; f[8 + j] = (float)v1[j]; }
  float m = f[0];
#pragma unroll
  for (int j = 1; j < 16; ++j) m = fmaxf(m, f[j]);
#pragma unroll
  for (int o = 32; o; o >>= 1) m = fmaxf(m, __shfl_xor(m, o, 64));
  float sum = 0.f;
#pragma unroll
  for (int j = 0; j < 16; ++j) { f[j] = __expf(f[j] - m); sum += f[j]; }
#pragma unroll
  for (int o = 32; o; o >>= 1) sum += __shfl_xor(sum, o, 64);
  const float inv = 1.0f / sum;
#pragma unroll
  for (int j = 0; j < 8; ++j) { v0[j] = (bf16)(f[j] * inv); v1[j] = (bf16)(f[8 + j] * inv); }
  *(bf16x8*)r = v0;
  *(bf16x8*)(r + 8) = v1;
}

extern "C" void kernel_launch(void* const* d_in, const int* in_sizes, int n_in,
                              void* d_out, int out_size, void* d_ws, size_t ws_size,
                              hipStream_t stream) {
  const float* key   = (const float*)d_in[0];
  const float* query = (const float*)d_in[1];
  const float* value = (const float*)d_in[2];
  const int*   pad   = (const int*)d_in[3];
  const float* Wk    = (const float*)d_in[4];
  const float* Wq    = (const float*)d_in[5];
  const float* Wv    = (const float*)d_in[6];
  float* out = (float*)d_out;

  // ws (bf16 elems): Wk,Wq,Wv (1M each) | q 16M | k 16M | vT 16M | S 16M
  // S doubles as bf16-X scratch during projections (not live until qk).
  bf16* Wkb = (bf16*)d_ws;
  bf16* Wqb = Wkb + (1 << 20);
  bf16* Wvb = Wqb + (1 << 20);
  bf16* qb  = Wvb + (1 << 20);
  bf16* kb  = qb  + (16 << 20);
  bf16* vT  = kb  + (16 << 20);
  bf16* S   = vT  + (16 << 20);
  bf16* Xb  = S;

  hipFuncSetAttribute(reinterpret_cast<const void*>(&gemm8<0>),
                      hipFuncAttributeMaxDynamicSharedMemorySize, 131072);
  hipFuncSetAttribute(reinterpret_cast<const void*>(&gemm8<1>),
                      hipFuncAttributeMaxDynamicSharedMemorySize, 131072);
  hipFuncSetAttribute(reinterpret_cast<const void*>(&gemm8<2>),
                      hipFuncAttributeMaxDynamicSharedMemorySize, 131072);
  hipFuncSetAttribute(reinterpret_cast<const void*>(&gemm8<3>),
                      hipFuncAttributeMaxDynamicSharedMemorySize, 131072);

  cvt_kernel<<<512, 256, 0, stream>>>(Wk, Wkb, 1 << 20);
  cvt_kernel<<<512, 256, 0, stream>>>(Wq, Wqb, 1 << 20);
  cvt_kernel<<<512, 256, 0, stream>>>(Wv, Wvb, 1 << 20);

  cvt_kernel<<<8192, 256, 0, stream>>>(query, Xb, 16 << 20);
  gemm8<0><<<256, 512, 131072, stream>>>(Xb, Wqb, qb, nullptr, nullptr);
  cvt_kernel<<<8192, 256, 0, stream>>>(key, Xb, 16 << 20);
  gemm8<0><<<256, 512, 131072, stream>>>(Xb, Wkb, kb, nullptr, nullptr);
  cvt_kernel<<<8192, 256, 0, stream>>>(value, Xb, 16 << 20);
  gemm8<1><<<256, 512, 131072, stream>>>(Xb, Wvb, vT, nullptr, nullptr);

  gemm8<2><<<256, 512, 131072, stream>>>(qb, kb, S, nullptr, pad);
  corner_kernel<<<48, 64, 0, stream>>>(qb, kb, pad, S);
  softmax_kernel<<<4096, 256, 0, stream>>>(S);
  gemm8<3><<<256, 512, 131072, stream>>>(S, vT, nullptr, out, nullptr);
}

// Round 4
// 261.190 us; speedup vs baseline: 1.5246x; 1.1882x over previous
//
#include <hip/hip_runtime.h>
#include <hip/hip_bf16.h>
#include <stdint.h>

typedef __bf16 bf16;
typedef __attribute__((ext_vector_type(8))) __bf16 bf16x8;
typedef __attribute__((ext_vector_type(4))) __bf16 bf16x4;
typedef __attribute__((ext_vector_type(4))) float  f32x4;

// ---- async global->LDS, 16B per lane, dest = wave-uniform base (+ lane*16 in HW) ----
static __device__ __forceinline__ void gll16(const void* g, void* lds_base) {
  __builtin_amdgcn_global_load_lds((__attribute__((address_space(1))) void*)g,
                                   (__attribute__((address_space(3))) void*)lds_base,
                                   16, 0, 0);
}

// ============================================================================
// 256x256 BT-GEMM (D = A * B^T, both K-contiguous, ld=1024), BK=64, 8 waves
// (2M x 4N), 2 phases per K-tile (B quarter held in regs across both phases
// -> LDS read traffic halved vs 4-quadrant), double-buffered 128 KiB LDS,
// row&7 XOR-swizzle (full 32-bank coverage; linear gll dest + inverse-swizzled
// global src + swizzled ds_read), counted vmcnt(4) once per K-tile.
// Staging region-safety: Ph1 stages A(u+1) into the OTHER slot (its rows were
// last read in u-1 Ph2); Ph2 stages B(u+2) into the CURRENT slot (B rows were
// consumed in Ph1). Per-wave FIFO: vmcnt(4) at tile end retires A(u+1),B(u+1).
// VARIANT: 0 proj -> Cb row-major [M][1024] bf16
//          1 proj -> Cb = per-batch transposed v^T [b][h][t] bf16
//          2 qk   -> Cb = S bf16 (scale, causal diag=+1, padding mask);
//                    upper-triangle tiles are -inf fill-only blocks
//          3 pv   -> Cf = O f32, K-loop causally truncated
// ============================================================================
#define MFMA_CLUSTER(MQ)                                                       \
  __builtin_amdgcn_s_barrier();                                                \
  asm volatile("s_waitcnt lgkmcnt(0)" ::: "memory");                           \
  __builtin_amdgcn_sched_barrier(0);                                           \
  __builtin_amdgcn_s_setprio(1);                                               \
  _Pragma("unroll") for (int i_ = 0; i_ < 4; ++i_)                             \
  _Pragma("unroll") for (int n_ = 0; n_ < 4; ++n_)                             \
  _Pragma("unroll") for (int kh_ = 0; kh_ < 2; ++kh_)                          \
    acc[(MQ) * 4 + i_][n_] = __builtin_amdgcn_mfma_f32_16x16x32_bf16(          \
        af[i_][kh_], bfr[n_][kh_], acc[(MQ) * 4 + i_][n_], 0, 0, 0);           \
  __builtin_amdgcn_s_setprio(0);

template <int VARIANT>
__global__ __launch_bounds__(512, 2) void gemm8(const bf16* __restrict__ A,
                                                const bf16* __restrict__ B,
                                                bf16* __restrict__ Cb,
                                                float* __restrict__ Cf,
                                                const int* __restrict__ pad) {
  extern __shared__ char smem[];         // A: 2 x 32KB | B: 2 x 32KB
  char* ldsA = smem;
  char* ldsB = smem + 65536;

  const int tid = threadIdx.x;
  const int lane = tid & 63, wave = tid >> 6;
  const int lo = lane & 15, hi = lane >> 4;
  const int wmi = wave >> 2, wni = wave & 3;
  const int swz = (lo & 7) << 4;         // read-side XOR: (row&7)<<4, row&7 == lo&7

  // XCD-chunked bijective swizzle (gridDim.x % 8 == 0 for all launches)
  const int nwg = gridDim.x;
  const int id = (blockIdx.x % 8) * (nwg >> 3) + blockIdx.x / 8;

  int row0, col0, nt, b = 0;
  if (VARIANT <= 1) {
    row0 = (id >> 2) * 256; col0 = (id & 3) * 256; nt = 16;
  } else {
    b = id >> 4;
    const int r = id & 15, it = r >> 2, jt = r & 3;
    row0 = it * 256; col0 = jt * 256;
    nt = (VARIANT == 3) ? min(16, 6 + 4 * it) : 16;
    if (VARIANT == 2 && jt > it) {
      // fully-masked tile (except the jt==it+1 corner, fixed by corner_kernel)
      bf16* Sb = Cb + ((size_t)b << 20);
      const bf16 NI = (bf16)(-__builtin_inff());
      bf16x8 fill = { NI, NI, NI, NI, NI, NI, NI, NI };
#pragma unroll
      for (int q = 0; q < 16; ++q) {
        const int off = (q * 512 + tid) * 8;
        const int rr = off >> 8, cc = off & 255;
        *(bf16x8*)(Sb + (size_t)(row0 + rr) * 1024 + col0 + cc) = fill;
      }
      return;
    }
  }
  const bf16* Ap = A + ((size_t)b << 20) + (size_t)row0 * 1024;
  const bf16* Bp = B + ((size_t)b << 20) + (size_t)col0 * 1024;
  const int ntm1 = nt - 1;

  // stage one full 256x64 operand K-tile (32KB): 4 gll/wave, linear LDS dest,
  // inverse-swizzled global source (same involution as the read-side XOR).
  auto stgA = [&](int tidx, int slot) {
    const int tc = tidx > ntm1 ? ntm1 : tidx;   // clamped re-stage: slot never read again
#pragma unroll
    for (int r = 0; r < 4; ++r) {
      const int x  = (wave * 4 + r) * 1024 + lane * 16;
      const int xs = x ^ (((x >> 7) & 7) << 4);
      gll16((const char*)Ap + (size_t)(xs >> 7) * 2048 + (size_t)tc * 128 + (xs & 127),
            ldsA + slot * 32768 + (wave * 4 + r) * 1024);
    }
  };
  auto stgB = [&](int tidx, int slot) {
    const int tc = tidx > ntm1 ? ntm1 : tidx;
#pragma unroll
    for (int r = 0; r < 4; ++r) {
      const int x  = (wave * 4 + r) * 1024 + lane * 16;
      const int xs = x ^ (((x >> 7) & 7) << 4);
      gll16((const char*)Bp + (size_t)(xs >> 7) * 2048 + (size_t)tc * 128 + (xs & 127),
            ldsB + slot * 32768 + (wave * 4 + r) * 1024);
    }
  };

  f32x4 acc[8][4] = {};

  // prologue: establish steady-state invariant (tile0 landed, B(1) in flight)
  stgB(0, 0);
  stgA(0, 0);
  stgB(1, 1);
  asm volatile("s_waitcnt vmcnt(4)" ::: "memory");   // retire B(0),A(0); keep B(1)
  __builtin_amdgcn_s_barrier();

  bf16x8 af[4][2], bfr[4][2];
#pragma unroll 2
  for (int u = 0; u < nt; ++u) {
    const int cur = u & 1;
    // ---- Phase 1: A rows [wmi*128, +64) + ALL of wave's B quarter ----
#pragma unroll
    for (int i_ = 0; i_ < 4; ++i_)
#pragma unroll
      for (int kh_ = 0; kh_ < 2; ++kh_) {
        const int row_ = wmi * 128 + i_ * 16 + lo;
        af[i_][kh_] = *(const bf16x8*)(ldsA + cur * 32768 +
                                       ((row_ * 128 + kh_ * 64 + hi * 16) ^ swz));
      }
#pragma unroll
    for (int n_ = 0; n_ < 4; ++n_)
#pragma unroll
      for (int kh_ = 0; kh_ < 2; ++kh_) {
        const int row_ = wni * 64 + n_ * 16 + lo;
        bfr[n_][kh_] = *(const bf16x8*)(ldsB + cur * 32768 +
                                        ((row_ * 128 + kh_ * 64 + hi * 16) ^ swz));
      }
    stgA(u + 1, cur ^ 1);
    MFMA_CLUSTER(0)
    __builtin_amdgcn_s_barrier();
    // ---- Phase 2: A rows [wmi*128+64, +64), reuse bfr from registers ----
#pragma unroll
    for (int i_ = 0; i_ < 4; ++i_)
#pragma unroll
      for (int kh_ = 0; kh_ < 2; ++kh_) {
        const int row_ = wmi * 128 + 64 + i_ * 16 + lo;
        af[i_][kh_] = *(const bf16x8*)(ldsA + cur * 32768 +
                                       ((row_ * 128 + kh_ * 64 + hi * 16) ^ swz));
      }
    stgB(u + 2, cur);
    MFMA_CLUSTER(1)
    asm volatile("s_waitcnt vmcnt(4)" ::: "memory");  // retire A(u+1),B(u+1); keep B(u+2)
    __builtin_amdgcn_s_barrier();
  }

  // ---- epilogue ----
  if (VARIANT == 0) {
#pragma unroll
    for (int m = 0; m < 8; ++m)
#pragma unroll
      for (int n = 0; n < 4; ++n) {
        const int c = col0 + wni * 64 + n * 16 + lo;
        const int rbase = row0 + wmi * 128 + m * 16 + hi * 4;
#pragma unroll
        for (int j = 0; j < 4; ++j)
          Cb[(size_t)(rbase + j) * 1024 + c] = (bf16)acc[m][n][j];
      }
  } else if (VARIANT == 1) {
#pragma unroll
    for (int m = 0; m < 8; ++m)
#pragma unroll
      for (int n = 0; n < 4; ++n) {
        const int r = row0 + wmi * 128 + m * 16 + hi * 4;
        const int c = col0 + wni * 64 + n * 16 + lo;
        const int bb = r >> 10, tt = r & 1023;
        bf16x4 h = { (bf16)acc[m][n][0], (bf16)acc[m][n][1],
                     (bf16)acc[m][n][2], (bf16)acc[m][n][3] };
        *(bf16x4*)(Cb + ((size_t)bb << 20) + ((size_t)c << 10) + tt) = h;
      }
  } else if (VARIANT == 2) {
    const float NINF = -__builtin_inff();
#pragma unroll
    for (int n = 0; n < 4; ++n) {
      const int s = col0 + wni * 64 + n * 16 + lo;
      const int pd = pad[(b << 10) + s];
#pragma unroll
      for (int m = 0; m < 8; ++m) {
        const int tbase = row0 + wmi * 128 + m * 16 + hi * 4;
#pragma unroll
        for (int j = 0; j < 4; ++j) {
          float v = acc[m][n][j] * 0.03125f;          // 1/sqrt(1024)
          if (s > tbase + j + 1 || pd != 0) v = NINF;
          Cb[((size_t)b << 20) + (size_t)(tbase + j) * 1024 + s] = (bf16)v;
        }
      }
    }
  } else {
#pragma unroll
    for (int m = 0; m < 8; ++m)
#pragma unroll
      for (int n = 0; n < 4; ++n) {
        const int h2 = col0 + wni * 64 + n * 16 + lo;
        const int tbase = row0 + wmi * 128 + m * 16 + hi * 4;
#pragma unroll
        for (int j = 0; j < 4; ++j)
          Cf[((size_t)b << 20) + (size_t)(tbase + j) * 1024 + h2] = acc[m][n][j];
      }
  }
  asm volatile("s_waitcnt vmcnt(0)" ::: "memory");   // drain clamped stages before exit
}

// ---- fp32 -> bf16 elementwise ----
__global__ __launch_bounds__(256) void cvt_kernel(const float* __restrict__ src,
                                                  bf16* __restrict__ dst, int n) {
  const int i = (blockIdx.x * 256 + threadIdx.x) * 8;
  if (i >= n) return;
  const f32x4 a = *(const f32x4*)(src + i);
  const f32x4 b = *(const f32x4*)(src + i + 4);
  bf16x8 o = { (bf16)a[0], (bf16)a[1], (bf16)a[2], (bf16)a[3],
               (bf16)b[0], (bf16)b[1], (bf16)b[2], (bf16)b[3] };
  *(bf16x8*)(dst + i) = o;
}

// ---- the single valid element on each jt==it+1 tile: S[t=it*256+255][s=(it+1)*256] ----
__global__ __launch_bounds__(64) void corner_kernel(const bf16* __restrict__ Q,
                                                    const bf16* __restrict__ K,
                                                    const int* __restrict__ pad,
                                                    bf16* __restrict__ S) {
  const int b = blockIdx.x / 3, it = blockIdx.x % 3;
  const int t = it * 256 + 255, s = (it + 1) * 256;
  const int lane = threadIdx.x;
  const bf16* q = Q + ((size_t)b << 20) + (size_t)t * 1024 + lane * 16;
  const bf16* k = K + ((size_t)b << 20) + (size_t)s * 1024 + lane * 16;
  bf16x8 q0 = *(const bf16x8*)q, q1 = *(const bf16x8*)(q + 8);
  bf16x8 k0 = *(const bf16x8*)k, k1 = *(const bf16x8*)(k + 8);
  float d = 0.f;
#pragma unroll
  for (int j = 0; j < 8; ++j) d += (float)q0[j] * (float)k0[j] + (float)q1[j] * (float)k1[j];
#pragma unroll
  for (int o = 32; o; o >>= 1) d += __shfl_xor(d, o, 64);
  if (lane == 0) {
    float v = d * 0.03125f;
    if (pad[(b << 10) + s] != 0) v = -__builtin_inff();
    S[((size_t)b << 20) + (size_t)t * 1024 + s] = (bf16)v;
  }
}

// ---- row softmax in place: one wave per 1024-wide row ----
__global__ __launch_bounds__(256) void softmax_kernel(bf16* __restrict__ S) {
  const int row  = blockIdx.x * 4 + (threadIdx.x >> 6);
  const int lane = threadIdx.x & 63;
  bf16* r = S + (size_t)row * 1024 + lane * 16;
  bf16x8 v0 = *(const bf16x8*)r;
  bf16x8 v1 = *(const bf16x8*)(r + 8);
  float f[16];
#pragma unroll
  for (int j = 0; j < 8; ++j) { f[j] = (float)v0[j]; f[8 + j] = (float)v1[j]; }
  float m = f[0];
#pragma unroll
  for (int j = 1; j < 16; ++j) m = fmaxf(m, f[j]);
#pragma unroll
  for (int o = 32; o; o >>= 1) m = fmaxf(m, __shfl_xor(m, o, 64));
  float sum = 0.f;
#pragma unroll
  for (int j = 0; j < 16; ++j) { f[j] = __expf(f[j] - m); sum += f[j]; }
#pragma unroll
  for (int o = 32; o; o >>= 1) sum += __shfl_xor(sum, o, 64);
  const float inv = 1.0f / sum;
#pragma unroll
  for (int j = 0; j < 8; ++j) { v0[j] = (bf16)(f[j] * inv); v1[j] = (bf16)(f[8 + j] * inv); }
  *(bf16x8*)r = v0;
  *(bf16x8*)(r + 8) = v1;
}

extern "C" void kernel_launch(void* const* d_in, const int* in_sizes, int n_in,
                              void* d_out, int out_size, void* d_ws, size_t ws_size,
                              hipStream_t stream) {
  const float* key   = (const float*)d_in[0];
  const float* query = (const float*)d_in[1];
  const float* value = (const float*)d_in[2];
  const int*   pad   = (const int*)d_in[3];
  const float* Wk    = (const float*)d_in[4];
  const float* Wq    = (const float*)d_in[5];
  const float* Wv    = (const float*)d_in[6];
  float* out = (float*)d_out;

  // ws (bf16 elems): Wk,Wq,Wv (1M each) | q 16M | k 16M | vT 16M | S 16M
  // S doubles as bf16-X scratch during projections (not live until qk).
  bf16* Wkb = (bf16*)d_ws;
  bf16* Wqb = Wkb + (1 << 20);
  bf16* Wvb = Wqb + (1 << 20);
  bf16* qb  = Wvb + (1 << 20);
  bf16* kb  = qb  + (16 << 20);
  bf16* vT  = kb  + (16 << 20);
  bf16* S   = vT  + (16 << 20);
  bf16* Xb  = S;

  hipFuncSetAttribute(reinterpret_cast<const void*>(&gemm8<0>),
                      hipFuncAttributeMaxDynamicSharedMemorySize, 131072);
  hipFuncSetAttribute(reinterpret_cast<const void*>(&gemm8<1>),
                      hipFuncAttributeMaxDynamicSharedMemorySize, 131072);
  hipFuncSetAttribute(reinterpret_cast<const void*>(&gemm8<2>),
                      hipFuncAttributeMaxDynamicSharedMemorySize, 131072);
  hipFuncSetAttribute(reinterpret_cast<const void*>(&gemm8<3>),
                      hipFuncAttributeMaxDynamicSharedMemorySize, 131072);

  cvt_kernel<<<512, 256, 0, stream>>>(Wk, Wkb, 1 << 20);
  cvt_kernel<<<512, 256, 0, stream>>>(Wq, Wqb, 1 << 20);
  cvt_kernel<<<512, 256, 0, stream>>>(Wv, Wvb, 1 << 20);

  cvt_kernel<<<8192, 256, 0, stream>>>(query, Xb, 16 << 20);
  gemm8<0><<<256, 512, 131072, stream>>>(Xb, Wqb, qb, nullptr, nullptr);
  cvt_kernel<<<8192, 256, 0, stream>>>(key, Xb, 16 << 20);
  gemm8<0><<<256, 512, 131072, stream>>>(Xb, Wkb, kb, nullptr, nullptr);
  cvt_kernel<<<8192, 256, 0, stream>>>(value, Xb, 16 << 20);
  gemm8<1><<<256, 512, 131072, stream>>>(Xb, Wvb, vT, nullptr, nullptr);

  gemm8<2><<<256, 512, 131072, stream>>>(qb, kb, S, nullptr, pad);
  corner_kernel<<<48, 64, 0, stream>>>(qb, kb, pad, S);
  softmax_kernel<<<4096, 256, 0, stream>>>(S);
  gemm8<3><<<256, 512, 131072, stream>>>(S, vT, nullptr, out, nullptr);
}